// Round 9
// baseline (387.333 us; speedup 1.0000x reference)
//
#include <hip/hip_runtime.h>
#include <hip/hip_bf16.h>
#include <stdint.h>

// ReadoutLayer: Wx = x @ W^T (+b cancels under BN), BatchNorm(train) over B*T,
// then ut = a*ut + (1-a)*wxn per t with acc += softmax(ut, axis=H).
// R13: BARRIER-FREE gemm. Five pipelines (R4..R12) all pinned at 90-115us /
// ~1.6TB/s; the shared invariant was the per-slab lgkmcnt+s_barrier lockstep
// for the A LDS tile (~5000cy slab period vs ~200cy of work). Fix: drop A
// staging -- each lane loads its A fragment DIRECT from X (2xfloat4 per
// (rt,kh), in-reg bf16 cvt = same cast as staging -> bit-identical). Zero
// barriers/LDS/ds-ops in the K loop; waves free-run; A+B reg double-buffered
// (WAR-safe order cvt->loadA->mfma->loadB). 8x A redundancy absorbed by L1
// (8KB slab tile shared by the block's 8 waves on one CU).
// Tail = R12's proven split kernels; wcvt_k zeroes sums+out (no memsets).

namespace {
constexpr int kB = 32;
constexpr int kT = 2000;
constexpr int kD = 512;
constexpr int kH = 512;
constexpr int kM = kB * kT;   // 64000 rows
constexpr int kBM = 64;       // rows per gemm block
constexpr int kNB = kM / kBM; // 1000 blocks
constexpr int kL = 16;        // chunk length (divides kT; chunks never straddle b)
constexpr int kC = kT / kL;   // 125 chunks per batch
constexpr int kG = 5;         // chunks per soft_k block
constexpr int kNG = kC / kG;  // 25 groups per batch -> 800 soft blocks
constexpr float kALo = 0.81873075307798182f;  // exp(-1/5)
constexpr float kAHi = 0.96078943915232320f;  // exp(-1/25)

typedef __bf16 bf16x4 __attribute__((ext_vector_type(4)));
typedef __bf16 bf16x8 __attribute__((ext_vector_type(8)));
typedef float floatx16 __attribute__((ext_vector_type(16)));

__device__ __forceinline__ float bf2f(unsigned short u) {
  return __builtin_bit_cast(float, (unsigned)u << 16);
}
__device__ __forceinline__ float clipa(float a) {
  return fminf(fmaxf(a, kALo), kAHi);
}
__device__ __forceinline__ float pow16(float a) {
  const float a2 = a * a, a4 = a2 * a2, a8 = a4 * a4;
  return a8 * a8;
}

// ---------- K0: W f32 -> bf16 permuted Wbf2[k8][h][8]; zero sums+out ----------
__global__ __launch_bounds__(256) void wcvt_k(const float* __restrict__ W,
                                              __bf16* __restrict__ Wbf,
                                              float* __restrict__ sums,
                                              float* __restrict__ out) {
  const int t = blockIdx.x * 256 + threadIdx.x;  // 32768 threads
  if (t < 2 * kH) sums[t] = 0.f;
  if (t < kB * kH) out[t] = 0.f;
  const float4 a0 = ((const float4*)W)[t * 2];
  const float4 a1 = ((const float4*)W)[t * 2 + 1];
  bf16x8 v;
  v[0] = (__bf16)a0.x; v[1] = (__bf16)a0.y; v[2] = (__bf16)a0.z; v[3] = (__bf16)a0.w;
  v[4] = (__bf16)a1.x; v[5] = (__bf16)a1.y; v[6] = (__bf16)a1.z; v[7] = (__bf16)a1.w;
  const int h = t >> 6, k8 = t & 63;
  *(bf16x8*)(Wbf + ((size_t)k8 * 512 + h) * 8) = v;  // scattered 16B: one-time
}

// ---------- K1: GEMM 64x512/block, BARRIER-FREE, A+B direct-to-reg ----------
// 512 threads = 8 waves; wave w: col-tiles ct0=w*2..+2, row-tiles rt=0..1.
// No LDS in the K loop; each wave free-runs.
__global__ __launch_bounds__(512, 2) void gemm_k(const float* __restrict__ X,
                                                 const __bf16* __restrict__ Wbf,
                                                 const float* __restrict__ alpha,
                                                 unsigned short* __restrict__ Wxb,
                                                 float* __restrict__ vbuf,
                                                 float* __restrict__ partial) {
  __shared__ float sred[2][kH];  // epilogue only
  const int tid = threadIdx.x;
  const size_t row0 = (size_t)blockIdx.x * kBM;
  const int w = tid >> 6, L = tid & 63;
  const int ct0 = w * 2;
  const int lhalf = L >> 5, l32 = L & 31;

  floatx16 acc[2][2] = {};
  // per-lane A row bases (rt=0,1) and k-column offset lhalf*8
  const float* xr0 = X + (row0 + l32) * kD + lhalf * 8;
  const float* xr1 = X + (row0 + 32 + l32) * kD + lhalf * 8;
  const __bf16* bptr = Wbf + ((size_t)(ct0 * 32) + l32) * 8;

  float4 aE[4][2], aO[4][2];  // [rt*2+kh][half] f32 A fragments (32 VGPR each)
  bf16x8 bE[4], bO[4];        // B fragments (16 VGPR each)

  auto loadA = [&](float4 (*dst)[2], int s) {
    // fragment (rt,kh): rows rt*32+l32, k = s*32 + kh*16 + lhalf*8 .. +8
#pragma unroll
    for (int rt = 0; rt < 2; ++rt) {
      const float* xr = rt ? xr1 : xr0;
#pragma unroll
      for (int kh = 0; kh < 2; ++kh) {
        const float* p = xr + s * 32 + kh * 16;
        dst[rt * 2 + kh][0] = *(const float4*)p;
        dst[rt * 2 + kh][1] = *(const float4*)(p + 4);
      }
    }
  };
  auto loadB = [&](bf16x8* dst, int s) {
#pragma unroll
    for (int kh = 0; kh < 2; ++kh) {
      const int kq = kh * 2 + lhalf;
      const __bf16* bq = bptr + (size_t)(s * 4 + kq) * 4096;
      dst[kh * 2 + 0] = *(const bf16x8*)bq;
      dst[kh * 2 + 1] = *(const bf16x8*)(bq + 256);  // +32 chunks = col+32
    }
  };
  auto cvt8 = [](const float4 (&f)[2]) {
    bf16x8 v;
    v[0] = (__bf16)f[0].x; v[1] = (__bf16)f[0].y;
    v[2] = (__bf16)f[0].z; v[3] = (__bf16)f[0].w;
    v[4] = (__bf16)f[1].x; v[5] = (__bf16)f[1].y;
    v[6] = (__bf16)f[1].z; v[7] = (__bf16)f[1].w;
    return v;
  };

  // prologue: slabs 0,1 in flight
  loadA(aE, 0); loadB(bE, 0);
  loadA(aO, 1); loadB(bO, 1);

#pragma unroll 1
  for (int s = 0; s < 16; s += 2) {
    {  // ---- even slab s: consume aE/bE ----
      bf16x8 af[4];
#pragma unroll
      for (int f = 0; f < 4; ++f) af[f] = cvt8(aE[f]);  // frees aE
      if (s + 2 < 16) loadA(aE, s + 2);                  // overlaps MFMA
#pragma unroll
      for (int kh = 0; kh < 2; ++kh) {
        acc[0][0] = __builtin_amdgcn_mfma_f32_32x32x16_bf16(af[kh], bE[kh * 2 + 0], acc[0][0], 0, 0, 0);
        acc[0][1] = __builtin_amdgcn_mfma_f32_32x32x16_bf16(af[kh], bE[kh * 2 + 1], acc[0][1], 0, 0, 0);
        acc[1][0] = __builtin_amdgcn_mfma_f32_32x32x16_bf16(af[2 + kh], bE[kh * 2 + 0], acc[1][0], 0, 0, 0);
        acc[1][1] = __builtin_amdgcn_mfma_f32_32x32x16_bf16(af[2 + kh], bE[kh * 2 + 1], acc[1][1], 0, 0, 0);
      }
      if (s + 2 < 16) loadB(bE, s + 2);  // after bE's last read
    }
    {  // ---- odd slab s+1: consume aO/bO ----
      bf16x8 af[4];
#pragma unroll
      for (int f = 0; f < 4; ++f) af[f] = cvt8(aO[f]);
      if (s + 3 < 16) loadA(aO, s + 3);
#pragma unroll
      for (int kh = 0; kh < 2; ++kh) {
        acc[0][0] = __builtin_amdgcn_mfma_f32_32x32x16_bf16(af[kh], bO[kh * 2 + 0], acc[0][0], 0, 0, 0);
        acc[0][1] = __builtin_amdgcn_mfma_f32_32x32x16_bf16(af[kh], bO[kh * 2 + 1], acc[0][1], 0, 0, 0);
        acc[1][0] = __builtin_amdgcn_mfma_f32_32x32x16_bf16(af[2 + kh], bO[kh * 2 + 0], acc[1][0], 0, 0, 0);
        acc[1][1] = __builtin_amdgcn_mfma_f32_32x32x16_bf16(af[2 + kh], bO[kh * 2 + 1], acc[1][1], 0, 0, 0);
      }
      if (s + 3 < 16) loadB(bO, s + 3);
    }
  }

  // ---- epilogue 1: column sums/sumsq -> LDS -> plain partial stores ----
  __syncthreads();
  sred[0][tid] = 0.f;
  sred[1][tid] = 0.f;
  __syncthreads();
#pragma unroll
  for (int c = 0; c < 2; ++c) {
    float s = 0.f, q = 0.f;
#pragma unroll
    for (int rt = 0; rt < 2; ++rt) {
#pragma unroll
      for (int r = 0; r < 16; ++r) {
        const float v = acc[rt][c][r];
        s += v;
        q += v * v;
      }
    }
    s += __shfl_xor(s, 32);
    q += __shfl_xor(q, 32);
    if (lhalf == 0) {
      atomicAdd(&sred[0][(ct0 + c) * 32 + l32], s);  // LDS atomics only
      atomicAdd(&sred[1][(ct0 + c) * 32 + l32], q);
    }
  }

  // ---- epilogue 1.5: fused raw chunk-EWMA (kL=16 rows per chunk) ----
  // v = sum_i a^(15-i) (1-a) wx_i; row-in-chunk i = (j&3)+8*(j>>2)+4*lhalf.
#pragma unroll
  for (int c = 0; c < 2; ++c) {
    const int col = (ct0 + c) * 32 + l32;
    const float a = clipa(alpha[col]);
    const float oma = 1.0f - a;
    const float a2 = a * a, a4 = a2 * a2, a8 = a4 * a4;
    float wgt[8];
    wgt[0] = a8 * a2 * a; wgt[1] = a8 * a2; wgt[2] = a8 * a; wgt[3] = a8;
    wgt[4] = a2 * a;      wgt[5] = a2;      wgt[6] = a;      wgt[7] = 1.0f;
    const float mult = (lhalf == 0) ? a4 * oma : oma;
#pragma unroll
    for (int j = 0; j < 8; ++j) wgt[j] *= mult;
#pragma unroll
    for (int rt = 0; rt < 2; ++rt) {
#pragma unroll
      for (int c32 = 0; c32 < 2; ++c32) {
        float S = 0.f;
#pragma unroll
        for (int j = 0; j < 8; ++j) S += wgt[j] * acc[rt][c][c32 * 8 + j];
        S += __shfl_xor(S, 32);
        if (lhalf == 0) {
          const int g = (int)blockIdx.x * 4 + rt * 2 + c32;  // global chunk id
          vbuf[(size_t)g * kH + col] = S;
        }
      }
    }
  }

  // ---- epilogue 2: store Wx bf16, packed dword pairs via shfl ----
  // C/D layout (32x32): col = lane&31, row = 4*(lane>>5) + (reg&3) + 8*(reg>>2)
#pragma unroll
  for (int rt = 0; rt < 2; ++rt) {
#pragma unroll
    for (int c = 0; c < 2; ++c) {
      const int col = (ct0 + c) * 32 + l32;
#pragma unroll
      for (int r = 0; r < 16; ++r) {
        const int row = rt * 32 + 4 * lhalf + (r & 3) + 8 * (r >> 2);
        const unsigned short u = __builtin_bit_cast(unsigned short, (__bf16)acc[rt][c][r]);
        const unsigned un = __shfl_down((unsigned)u, 1);
        if ((l32 & 1) == 0)
          *(unsigned*)(Wxb + (row0 + row) * (size_t)kH + col) = (unsigned)u | (un << 16);
      }
    }
  }
  __syncthreads();
  partial[(size_t)blockIdx.x * 1024 + tid] = sred[0][tid];
  partial[(size_t)blockIdx.x * 1024 + 512 + tid] = sred[1][tid];
}

// ---------- K2: reduce per-block partials (40 blocks x 25 rows = 1000) ----------
__global__ __launch_bounds__(512) void red1_k(const float* __restrict__ partial,
                                              float* __restrict__ sums) {
  const int tid = threadIdx.x;
  const int r0 = blockIdx.x * 25;
  float s0 = 0.f, s1 = 0.f;
#pragma unroll 5
  for (int r = 0; r < 25; ++r) {
    s0 += partial[(size_t)(r0 + r) * 1024 + tid];
    s1 += partial[(size_t)(r0 + r) * 1024 + 512 + tid];
  }
  atomicAdd(&sums[tid], s0);        // 40-deep contention: negligible
  atomicAdd(&sums[kH + tid], s1);
}

// ---------- K3: finalize BN params + chunk-boundary scan (fused) ----------
// grid = 32 (one block per batch); BN params computed redundantly per block.
// prm: [0]=scale [512]=shift [1024]=a [1536]=1-a  (written by block 0)
__global__ __launch_bounds__(512) void fin_scan_k(const float* __restrict__ sums,
                                                  const float* __restrict__ alpha,
                                                  const float* __restrict__ gamma,
                                                  const float* __restrict__ beta,
                                                  const float* __restrict__ ut0,
                                                  float* __restrict__ prm,
                                                  const float* __restrict__ vbuf,
                                                  float* __restrict__ ustart) {
  const int h = threadIdx.x;
  const int b = blockIdx.x;
  const float inv_n = 1.0f / (float)kM;
  const float mean = sums[h] * inv_n;
  const float var = sums[kH + h] * inv_n - mean * mean;
  const float sc = gamma[h] * rsqrtf(var + 1e-5f);
  const float sh = beta[h] - mean * sc;
  const float a = clipa(alpha[h]);
  if (b == 0) {
    prm[h] = sc;
    prm[kH + h] = sh;
    prm[2 * kH + h] = a;
    prm[3 * kH + h] = 1.0f - a;
  }
  const float a16 = pow16(a);
  const float shc = sh * (1.0f - a16);
  float u = ut0[(size_t)b * kH + h];
  float vc[kG];
#pragma unroll 1
  for (int cb = 0; cb < kC; cb += kG) {
#pragma unroll
    for (int j = 0; j < kG; ++j)
      vc[j] = vbuf[((size_t)b * kC + cb + j) * kH + h];  // independent, pipelined
    ustart[((size_t)b * kNG + cb / kG) * kH + h] = u;    // group-start u
#pragma unroll
    for (int j = 0; j < kG; ++j) u = a16 * u + sc * vc[j] + shc;
  }
}

// ---------- K4: softmax accumulation over 5 chunks + atomic out ----------
__global__ __launch_bounds__(512) void soft_k(const unsigned short* __restrict__ Wxb,
                                              const float* __restrict__ prm,
                                              const float* __restrict__ ustart,
                                              float* __restrict__ out) {
  __shared__ float part[kL][9];
  __shared__ float zinv[kL];
  const int bc = blockIdx.x;               // 0..799
  const int b = bc / kNG, grp = bc % kNG;
  const int h = threadIdx.x;
  const int wv = h >> 6, lane = h & 63;
  const float sc = prm[h], sh = prm[kH + h];
  const float a = prm[2 * kH + h], oma = prm[3 * kH + h];
  float u = ustart[(size_t)bc * kH + h];
  const unsigned short* base =
      Wxb + ((size_t)b * kT + (size_t)grp * kG * kL) * kH + h;
  float acc = 0.f;
#pragma unroll 1
  for (int cc = 0; cc < kG; ++cc) {
    float e[kL];
#pragma unroll
    for (int i = 0; i < kL; ++i) {
      const float wvx = bf2f(base[(size_t)(cc * kL + i) * kH]) * sc + sh;
      u = a * u + oma * wvx;
      e[i] = __expf(u);  // |u| <~ 2 after BN+EWMA damping
    }
#pragma unroll
    for (int i = 0; i < kL; ++i) {
      float s = e[i];
#pragma unroll
      for (int off = 32; off > 0; off >>= 1) s += __shfl_xor(s, off);
      if (lane == 0) part[i][wv] = s;
    }
    __syncthreads();
    if (h < kL) {
      float s = 0.f;
#pragma unroll
      for (int j = 0; j < 8; ++j) s += part[h][j];
      zinv[h] = 1.0f / s;
    }
    __syncthreads();
#pragma unroll
    for (int i = 0; i < kL; ++i) acc += e[i] * zinv[i];
    __syncthreads();  // rotation trivially race-free
  }
  atomicAdd(&out[(size_t)b * kH + h], acc);  // 25-deep per address
}

}  // namespace

extern "C" void kernel_launch(void* const* d_in, const int* in_sizes, int n_in,
                              void* d_out, int out_size, void* d_ws, size_t ws_size,
                              hipStream_t stream) {
  const float* x = (const float*)d_in[0];      // [32,2000,512]
  const float* Wm = (const float*)d_in[1];     // [512,512]
  // d_in[2] = b: unused — BN mean subtraction cancels the bias exactly
  const float* alpha = (const float*)d_in[3];
  const float* gamma = (const float*)d_in[4];
  const float* beta = (const float*)d_in[5];
  const float* ut0 = (const float*)d_in[6];
  float* out = (float*)d_out;                  // [32,1,512]

  float* wsp = (float*)d_ws;
  float* vbuf = wsp;                                   // 32*125*512 = 2,048,000 f
  float* ustart = vbuf + (size_t)kB * kC * kH;         // 32*25*512 = 409,600 f
  float* partial = ustart + (size_t)kB * kNG * kH;     // 1000*1024 f
  float* sums = partial + (size_t)1000 * 1024;         // 1024 f
  float* prm = sums + 2 * kH;                          // 2048 f
  __bf16* Wbf = (__bf16*)(prm + 4 * kH);               // 262144 bf16 (16B-aligned)
  unsigned short* Wxb = (unsigned short*)(Wbf + (size_t)kH * kD);  // 65.5 MB

  wcvt_k<<<128, 256, 0, stream>>>(Wm, Wbf, sums, out);  // also zeroes sums+out
  gemm_k<<<kNB, 512, 0, stream>>>(x, Wbf, alpha, Wxb, vbuf, partial);
  red1_k<<<40, 512, 0, stream>>>(partial, sums);
  fin_scan_k<<<kB, 512, 0, stream>>>(sums, alpha, gamma, beta, ut0, prm, vbuf, ustart);
  soft_k<<<kB * kNG, 512, 0, stream>>>(Wxb, prm, ustart, out);
}

// Round 10
// 332.245 us; speedup vs baseline: 1.1658x; 1.1658x over previous
//
#include <hip/hip_runtime.h>
#include <hip/hip_bf16.h>
#include <stdint.h>

// ReadoutLayer: Wx = x @ W^T (+b cancels under BN), BatchNorm(train) over B*T,
// then ut = a*ut + (1-a)*wxn per t with acc += softmax(ut, axis=H).
// R14: revert R13 (barrier-free gemm = 2x worse: per-lane A loads were 2KB-
// strided -> request amplification; MfmaUtil 7%). Base = R12 (302.9us best).
// This round: (1) soft_k rewritten barrier-free: ONE WAVE PER CHUNK, lane owns
// 8 cols -> coalesced ushort8 row loads, softmax denom = 6-level shfl_xor over
// the wave (all 512 h in-register), normalize immediately; zero LDS/barriers;
// 4000 independent waves. ustart per-chunk stored IN-PLACE in vbuf (no ws
// growth). (2) gemm: bijective XCD swizzle (1000=8x125): XCD gets contiguous
// row-blocks -> X/Wbf L2 locality. Bit-identical gemm math.

namespace {
constexpr int kB = 32;
constexpr int kT = 2000;
constexpr int kD = 512;
constexpr int kH = 512;
constexpr int kM = kB * kT;   // 64000 rows
constexpr int kBM = 64;       // rows per gemm block
constexpr int kNB = kM / kBM; // 1000 blocks = 8 x 125 (bijective XCD swizzle)
constexpr int kL = 16;        // chunk length (divides kT; chunks never straddle b)
constexpr int kC = kT / kL;   // 125 chunks per batch -> 4000 chunk units
constexpr int kG = 5;         // chunks per fin_scan prefetch group
constexpr float kALo = 0.81873075307798182f;  // exp(-1/5)
constexpr float kAHi = 0.96078943915232320f;  // exp(-1/25)

typedef __bf16 bf16x4 __attribute__((ext_vector_type(4)));
typedef __bf16 bf16x8 __attribute__((ext_vector_type(8)));
typedef unsigned short u16x8 __attribute__((ext_vector_type(8)));
typedef float floatx16 __attribute__((ext_vector_type(16)));

__device__ __forceinline__ float bf2f(unsigned short u) {
  return __builtin_bit_cast(float, (unsigned)u << 16);
}
__device__ __forceinline__ float clipa(float a) {
  return fminf(fmaxf(a, kALo), kAHi);
}
__device__ __forceinline__ float pow16(float a) {
  const float a2 = a * a, a4 = a2 * a2, a8 = a4 * a4;
  return a8 * a8;
}

// ---------- K0: W f32 -> bf16 permuted Wbf2[k8][h][8]; zero sums+out ----------
__global__ __launch_bounds__(256) void wcvt_k(const float* __restrict__ W,
                                              __bf16* __restrict__ Wbf,
                                              float* __restrict__ sums,
                                              float* __restrict__ out) {
  const int t = blockIdx.x * 256 + threadIdx.x;  // 32768 threads
  if (t < 2 * kH) sums[t] = 0.f;
  if (t < kB * kH) out[t] = 0.f;
  const float4 a0 = ((const float4*)W)[t * 2];
  const float4 a1 = ((const float4*)W)[t * 2 + 1];
  bf16x8 v;
  v[0] = (__bf16)a0.x; v[1] = (__bf16)a0.y; v[2] = (__bf16)a0.z; v[3] = (__bf16)a0.w;
  v[4] = (__bf16)a1.x; v[5] = (__bf16)a1.y; v[6] = (__bf16)a1.z; v[7] = (__bf16)a1.w;
  const int h = t >> 6, k8 = t & 63;
  *(bf16x8*)(Wbf + ((size_t)k8 * 512 + h) * 8) = v;  // scattered 16B: one-time
}

// ---------- K1: GEMM 64x512/block (R12 structure) + XCD swizzle ----------
// 512 threads = 8 waves; wave w: col-tiles ct0=w*2..+2, row-tiles rt=0..1.
__global__ __launch_bounds__(512, 4) void gemm_k(const float* __restrict__ X,
                                                 const __bf16* __restrict__ Wbf,
                                                 const float* __restrict__ alpha,
                                                 unsigned short* __restrict__ Wxb,
                                                 float* __restrict__ vbuf,
                                                 float* __restrict__ partial) {
  __shared__ alignas(16) __bf16 As2[2][4][65][8];  // [buf][kq][row+pad][k%8]
  __shared__ float sred[2][kH];
  const int tid = threadIdx.x;
  // bijective XCD swizzle: XCD (bid&7) gets contiguous block range (bid>>3)
  const int swz = (blockIdx.x & 7) * (kNB / 8) + (blockIdx.x >> 3);
  const size_t row0 = (size_t)swz * kBM;
  const int w = tid >> 6, L = tid & 63;
  const int ct0 = w * 2;
  const int lhalf = L >> 5, l32 = L & 31;
  const int arow = tid >> 3, acol = (tid & 7) * 4;  // A staging: 1 float4/thread
  const int akq = acol >> 3, aoff = acol & 7;

  floatx16 acc[2][2] = {};
  const float* xptr = X + (row0 + arow) * kD + acol;
  const __bf16* bptr = Wbf + ((size_t)(ct0 * 32) + l32) * 8;

  bf16x8 bE[4], bO[4];  // B fragments, even/odd slab double-buffer
  auto loadB = [&](bf16x8* dst, int s) {
#pragma unroll
    for (int kh = 0; kh < 2; ++kh) {
      const int kq = kh * 2 + lhalf;
      const __bf16* bq = bptr + (size_t)(s * 4 + kq) * 4096;
      dst[kh * 2 + 0] = *(const bf16x8*)bq;
      dst[kh * 2 + 1] = *(const bf16x8*)(bq + 256);  // +32 chunks = col+32
    }
  };
  auto stage = [&](int bufIdx, const float4& a) {
    bf16x4 av;
    av[0] = (__bf16)a.x; av[1] = (__bf16)a.y;
    av[2] = (__bf16)a.z; av[3] = (__bf16)a.w;
    *(bf16x4*)&As2[bufIdx][akq][arow][aoff] = av;
  };
  auto computeR = [&](int bufIdx, const bf16x8* bb) {
#pragma unroll
    for (int kh = 0; kh < 2; ++kh) {
      const int kq = kh * 2 + lhalf;
      const bf16x8 af0 = *(const bf16x8*)&As2[bufIdx][kq][l32][0];
      const bf16x8 af1 = *(const bf16x8*)&As2[bufIdx][kq][32 + l32][0];
      acc[0][0] = __builtin_amdgcn_mfma_f32_32x32x16_bf16(af0, bb[kh * 2 + 0], acc[0][0], 0, 0, 0);
      acc[0][1] = __builtin_amdgcn_mfma_f32_32x32x16_bf16(af0, bb[kh * 2 + 1], acc[0][1], 0, 0, 0);
      acc[1][0] = __builtin_amdgcn_mfma_f32_32x32x16_bf16(af1, bb[kh * 2 + 0], acc[1][0], 0, 0, 0);
      acc[1][1] = __builtin_amdgcn_mfma_f32_32x32x16_bf16(af1, bb[kh * 2 + 1], acc[1][1], 0, 0, 0);
    }
  };

  // prologue: B(0)->bE; stage A(0); X(1),X(2) in flight (2-deep)
  loadB(bE, 0);
  {
    const float4 a0 = *(const float4*)xptr;
    stage(0, a0);
  }
  float4 aA = *(const float4*)(xptr + 1 * 32);
  float4 aB = *(const float4*)(xptr + 2 * 32);
  asm volatile("s_waitcnt lgkmcnt(0)" ::: "memory");
  __builtin_amdgcn_s_barrier();

#pragma unroll 1
  for (int s = 0; s < 16; s += 2) {
    // ---- even slab s: B(s+1)->bO issued first (full slab to land) ----
    loadB(bO, s + 1);
    stage(1, aA);  // waits only aA's vmcnt; bO/aB stay in flight
    if (s + 3 < 16) aA = *(const float4*)(xptr + (s + 3) * 32);
    computeR(0, bE);
    asm volatile("s_waitcnt lgkmcnt(0)" ::: "memory");  // A ds_writes visible
    __builtin_amdgcn_s_barrier();                        // vmcnt NOT drained
    // ---- odd slab o=s+1: B(o+1)->bE; compute from bO ----
    const int o = s + 1;
    if (o < 15) {
      loadB(bE, o + 1);
      stage(0, aB);
      if (o + 3 < 16) aB = *(const float4*)(xptr + (o + 3) * 32);
    }
    computeR(1, bO);
    if (o < 15) {
      asm volatile("s_waitcnt lgkmcnt(0)" ::: "memory");
      __builtin_amdgcn_s_barrier();
    }
  }

  // ---- epilogue 1: column sums/sumsq -> LDS -> plain partial stores ----
  __syncthreads();
  sred[0][tid] = 0.f;
  sred[1][tid] = 0.f;
  __syncthreads();
#pragma unroll
  for (int c = 0; c < 2; ++c) {
    float s = 0.f, q = 0.f;
#pragma unroll
    for (int rt = 0; rt < 2; ++rt) {
#pragma unroll
      for (int r = 0; r < 16; ++r) {
        const float v = acc[rt][c][r];
        s += v;
        q += v * v;
      }
    }
    s += __shfl_xor(s, 32);
    q += __shfl_xor(q, 32);
    if (lhalf == 0) {
      atomicAdd(&sred[0][(ct0 + c) * 32 + l32], s);  // LDS atomics only
      atomicAdd(&sred[1][(ct0 + c) * 32 + l32], q);
    }
  }

  // ---- epilogue 1.5: fused raw chunk-EWMA (kL=16 rows per chunk) ----
  // v = sum_i a^(15-i) (1-a) wx_i; row-in-chunk i = (j&3)+8*(j>>2)+4*lhalf.
#pragma unroll
  for (int c = 0; c < 2; ++c) {
    const int col = (ct0 + c) * 32 + l32;
    const float a = clipa(alpha[col]);
    const float oma = 1.0f - a;
    const float a2 = a * a, a4 = a2 * a2, a8 = a4 * a4;
    float wgt[8];
    wgt[0] = a8 * a2 * a; wgt[1] = a8 * a2; wgt[2] = a8 * a; wgt[3] = a8;
    wgt[4] = a2 * a;      wgt[5] = a2;      wgt[6] = a;      wgt[7] = 1.0f;
    const float mult = (lhalf == 0) ? a4 * oma : oma;
#pragma unroll
    for (int j = 0; j < 8; ++j) wgt[j] *= mult;
#pragma unroll
    for (int rt = 0; rt < 2; ++rt) {
#pragma unroll
      for (int c32 = 0; c32 < 2; ++c32) {
        float S = 0.f;
#pragma unroll
        for (int j = 0; j < 8; ++j) S += wgt[j] * acc[rt][c][c32 * 8 + j];
        S += __shfl_xor(S, 32);
        if (lhalf == 0) {
          const int g = swz * 4 + rt * 2 + c32;  // global chunk id (swizzled rows)
          vbuf[(size_t)g * kH + col] = S;
        }
      }
    }
  }

  // ---- epilogue 2: store Wx bf16, packed dword pairs via shfl ----
  // C/D layout (32x32): col = lane&31, row = 4*(lane>>5) + (reg&3) + 8*(reg>>2)
#pragma unroll
  for (int rt = 0; rt < 2; ++rt) {
#pragma unroll
    for (int c = 0; c < 2; ++c) {
      const int col = (ct0 + c) * 32 + l32;
#pragma unroll
      for (int r = 0; r < 16; ++r) {
        const int row = rt * 32 + 4 * lhalf + (r & 3) + 8 * (r >> 2);
        const unsigned short u = __builtin_bit_cast(unsigned short, (__bf16)acc[rt][c][r]);
        const unsigned un = __shfl_down((unsigned)u, 1);
        if ((l32 & 1) == 0)
          *(unsigned*)(Wxb + (row0 + row) * (size_t)kH + col) = (unsigned)u | (un << 16);
      }
    }
  }
  __syncthreads();
  partial[(size_t)blockIdx.x * 1024 + tid] = sred[0][tid];
  partial[(size_t)blockIdx.x * 1024 + 512 + tid] = sred[1][tid];
}

// ---------- K2: reduce per-block partials (40 blocks x 25 rows = 1000) ----------
__global__ __launch_bounds__(512) void red1_k(const float* __restrict__ partial,
                                              float* __restrict__ sums) {
  const int tid = threadIdx.x;
  const int r0 = blockIdx.x * 25;
  float s0 = 0.f, s1 = 0.f;
#pragma unroll 5
  for (int r = 0; r < 25; ++r) {
    s0 += partial[(size_t)(r0 + r) * 1024 + tid];
    s1 += partial[(size_t)(r0 + r) * 1024 + 512 + tid];
  }
  atomicAdd(&sums[tid], s0);        // 40-deep contention: negligible
  atomicAdd(&sums[kH + tid], s1);
}

// ---------- K3: finalize BN params + chunk scan; ustart IN-PLACE in vbuf ----------
// grid = 32 (one block per batch). prm: [0]=scale [512]=shift [1024]=a [1536]=1-a.
// Per chunk: read v, overwrite slot with chunk-start u, advance u=a16*u+sc*v+shc.
__global__ __launch_bounds__(512) void fin_scan_k(const float* __restrict__ sums,
                                                  const float* __restrict__ alpha,
                                                  const float* __restrict__ gamma,
                                                  const float* __restrict__ beta,
                                                  const float* __restrict__ ut0,
                                                  float* __restrict__ prm,
                                                  float* __restrict__ vbuf) {
  const int h = threadIdx.x;
  const int b = blockIdx.x;
  const float inv_n = 1.0f / (float)kM;
  const float mean = sums[h] * inv_n;
  const float var = sums[kH + h] * inv_n - mean * mean;
  const float sc = gamma[h] * rsqrtf(var + 1e-5f);
  const float sh = beta[h] - mean * sc;
  const float a = clipa(alpha[h]);
  if (b == 0) {
    prm[h] = sc;
    prm[kH + h] = sh;
    prm[2 * kH + h] = a;
    prm[3 * kH + h] = 1.0f - a;
  }
  const float a16 = pow16(a);
  const float shc = sh * (1.0f - a16);
  float u = ut0[(size_t)b * kH + h];
  float vc[kG];
#pragma unroll 1
  for (int cb = 0; cb < kC; cb += kG) {
#pragma unroll
    for (int j = 0; j < kG; ++j)
      vc[j] = vbuf[((size_t)b * kC + cb + j) * kH + h];  // prefetch group
#pragma unroll
    for (int j = 0; j < kG; ++j) {
      vbuf[((size_t)b * kC + cb + j) * kH + h] = u;      // chunk-start u
      u = a16 * u + sc * vc[j] + shc;
    }
  }
}

// ---------- K4: softmax accumulation — ONE WAVE PER CHUNK, barrier-free ----------
// 1000 blocks x 256 threads = 4000 waves = 4000 chunk units (32 b x 125 c).
// Lane owns 8 columns (h = lane*8): row load = coalesced ushort8 (1 KB/wave);
// softmax denom = 6-level shfl_xor over the wave; normalize immediately.
// Zero LDS, zero barriers.
__global__ __launch_bounds__(256, 4) void soft_k(const unsigned short* __restrict__ Wxb,
                                                 const float* __restrict__ prm,
                                                 const float* __restrict__ ustart,
                                                 float* __restrict__ out) {
  const int tid = threadIdx.x;
  const int wv = tid >> 6, lane = tid & 63;
  const int unit = blockIdx.x * 4 + wv;       // 0..3999
  const int b = unit / kC, c = unit % kC;
  const int h0 = lane * 8;

  float sc[8], sh[8], av[8], om[8], u[8], acc[8];
  *(float4*)&sc[0] = *(const float4*)(prm + h0);
  *(float4*)&sc[4] = *(const float4*)(prm + h0 + 4);
  *(float4*)&sh[0] = *(const float4*)(prm + kH + h0);
  *(float4*)&sh[4] = *(const float4*)(prm + kH + h0 + 4);
  *(float4*)&av[0] = *(const float4*)(prm + 2 * kH + h0);
  *(float4*)&av[4] = *(const float4*)(prm + 2 * kH + h0 + 4);
  *(float4*)&om[0] = *(const float4*)(prm + 3 * kH + h0);
  *(float4*)&om[4] = *(const float4*)(prm + 3 * kH + h0 + 4);
  const float* up = ustart + ((size_t)b * kC + c) * kH + h0;
  *(float4*)&u[0] = *(const float4*)up;
  *(float4*)&u[4] = *(const float4*)(up + 4);
#pragma unroll
  for (int j = 0; j < 8; ++j) acc[j] = 0.f;

  const unsigned short* base = Wxb + ((size_t)b * kT + (size_t)c * kL) * kH + h0;
#pragma unroll
  for (int i = 0; i < kL; ++i) {
    const u16x8 v = *(const u16x8*)(base + (size_t)i * kH);
    float e[8];
    float ls = 0.f;
#pragma unroll
    for (int j = 0; j < 8; ++j) {
      const float wvx = bf2f(v[j]) * sc[j] + sh[j];
      u[j] = av[j] * u[j] + om[j] * wvx;
      e[j] = __expf(u[j]);  // |u| <~ 2 after BN+EWMA damping
      ls += e[j];
    }
#pragma unroll
    for (int off = 32; off > 0; off >>= 1) ls += __shfl_xor(ls, off);
    const float zi = 1.0f / ls;
#pragma unroll
    for (int j = 0; j < 8; ++j) acc[j] += e[j] * zi;
  }
#pragma unroll
  for (int j = 0; j < 8; ++j)
    atomicAdd(&out[(size_t)b * kH + h0 + j], acc[j]);  // 125-deep, time-spread
}

}  // namespace

extern "C" void kernel_launch(void* const* d_in, const int* in_sizes, int n_in,
                              void* d_out, int out_size, void* d_ws, size_t ws_size,
                              hipStream_t stream) {
  const float* x = (const float*)d_in[0];      // [32,2000,512]
  const float* Wm = (const float*)d_in[1];     // [512,512]
  // d_in[2] = b: unused — BN mean subtraction cancels the bias exactly
  const float* alpha = (const float*)d_in[3];
  const float* gamma = (const float*)d_in[4];
  const float* beta = (const float*)d_in[5];
  const float* ut0 = (const float*)d_in[6];
  float* out = (float*)d_out;                  // [32,1,512]

  float* wsp = (float*)d_ws;
  float* vbuf = wsp;                                   // 32*125*512 = 2,048,000 f
  float* partial = vbuf + (size_t)kB * kC * kH;        // 1000*1024 f
  float* sums = partial + (size_t)1000 * 1024;         // 1024 f
  float* prm = sums + 2 * kH;                          // 2048 f
  __bf16* Wbf = (__bf16*)(prm + 4 * kH);               // 262144 bf16 (16B-aligned)
  unsigned short* Wxb = (unsigned short*)(Wbf + (size_t)kH * kD);  // 65.5 MB

  wcvt_k<<<128, 256, 0, stream>>>(Wm, Wbf, sums, out);  // also zeroes sums+out
  gemm_k<<<kNB, 512, 0, stream>>>(x, Wbf, alpha, Wxb, vbuf, partial);
  red1_k<<<40, 512, 0, stream>>>(partial, sums);
  fin_scan_k<<<kB, 512, 0, stream>>>(sums, alpha, gamma, beta, ut0, prm, vbuf);
  soft_k<<<1000, 256, 0, stream>>>(Wxb, prm, vbuf, out);
}

// Round 11
// 300.207 us; speedup vs baseline: 1.2902x; 1.1067x over previous
//
#include <hip/hip_runtime.h>
#include <hip/hip_bf16.h>
#include <stdint.h>

// ReadoutLayer: Wx = x @ W^T (+b cancels under BN), BatchNorm(train) over B*T,
// then ut = a*ut + (1-a)*wxn per t with acc += softmax(ut, axis=H).
// R15: R14 post-mortem: XCD swizzle neutral; wave-per-chunk soft_k regressed
// +30us via 2.05M atomics 125-deep (R2/R3 failure mode reintroduced). Fix:
// keep R14's compute structure (4000 waves, coalesced ushort8 rows, shfl_xor
// denom, no main-loop LDS) but block = 320 thr = 5 waves = ONE GROUP (5 chunks,
// same batch): one 8KB LDS cross-wave reduce + single atomic set from wave 0
// -> 410K atomics 25-deep (R12's proven depth). gemm = R12 (91us, swizzle kept,
// neutral). red1/fin_scan unchanged; ustart per-chunk in-place in vbuf.

namespace {
constexpr int kB = 32;
constexpr int kT = 2000;
constexpr int kD = 512;
constexpr int kH = 512;
constexpr int kM = kB * kT;   // 64000 rows
constexpr int kBM = 64;       // rows per gemm block
constexpr int kNB = kM / kBM; // 1000 blocks = 8 x 125 (bijective XCD swizzle)
constexpr int kL = 16;        // chunk length (divides kT; chunks never straddle b)
constexpr int kC = kT / kL;   // 125 chunks per batch
constexpr int kG = 5;         // chunks per group (= waves per soft block)
constexpr int kNG = kC / kG;  // 25 groups per batch -> 800 soft blocks
constexpr float kALo = 0.81873075307798182f;  // exp(-1/5)
constexpr float kAHi = 0.96078943915232320f;  // exp(-1/25)

typedef __bf16 bf16x4 __attribute__((ext_vector_type(4)));
typedef __bf16 bf16x8 __attribute__((ext_vector_type(8)));
typedef unsigned short u16x8 __attribute__((ext_vector_type(8)));
typedef float floatx16 __attribute__((ext_vector_type(16)));

__device__ __forceinline__ float bf2f(unsigned short u) {
  return __builtin_bit_cast(float, (unsigned)u << 16);
}
__device__ __forceinline__ float clipa(float a) {
  return fminf(fmaxf(a, kALo), kAHi);
}
__device__ __forceinline__ float pow16(float a) {
  const float a2 = a * a, a4 = a2 * a2, a8 = a4 * a4;
  return a8 * a8;
}

// ---------- K0: W f32 -> bf16 permuted Wbf2[k8][h][8]; zero sums+out ----------
__global__ __launch_bounds__(256) void wcvt_k(const float* __restrict__ W,
                                              __bf16* __restrict__ Wbf,
                                              float* __restrict__ sums,
                                              float* __restrict__ out) {
  const int t = blockIdx.x * 256 + threadIdx.x;  // 32768 threads
  if (t < 2 * kH) sums[t] = 0.f;
  if (t < kB * kH) out[t] = 0.f;
  const float4 a0 = ((const float4*)W)[t * 2];
  const float4 a1 = ((const float4*)W)[t * 2 + 1];
  bf16x8 v;
  v[0] = (__bf16)a0.x; v[1] = (__bf16)a0.y; v[2] = (__bf16)a0.z; v[3] = (__bf16)a0.w;
  v[4] = (__bf16)a1.x; v[5] = (__bf16)a1.y; v[6] = (__bf16)a1.z; v[7] = (__bf16)a1.w;
  const int h = t >> 6, k8 = t & 63;
  *(bf16x8*)(Wbf + ((size_t)k8 * 512 + h) * 8) = v;  // scattered 16B: one-time
}

// ---------- K1: GEMM 64x512/block (R12 structure) + XCD swizzle ----------
// 512 threads = 8 waves; wave w: col-tiles ct0=w*2..+2, row-tiles rt=0..1.
__global__ __launch_bounds__(512, 4) void gemm_k(const float* __restrict__ X,
                                                 const __bf16* __restrict__ Wbf,
                                                 const float* __restrict__ alpha,
                                                 unsigned short* __restrict__ Wxb,
                                                 float* __restrict__ vbuf,
                                                 float* __restrict__ partial) {
  __shared__ alignas(16) __bf16 As2[2][4][65][8];  // [buf][kq][row+pad][k%8]
  __shared__ float sred[2][kH];
  const int tid = threadIdx.x;
  // bijective XCD swizzle: XCD (bid&7) gets contiguous block range (bid>>3)
  const int swz = (blockIdx.x & 7) * (kNB / 8) + (blockIdx.x >> 3);
  const size_t row0 = (size_t)swz * kBM;
  const int w = tid >> 6, L = tid & 63;
  const int ct0 = w * 2;
  const int lhalf = L >> 5, l32 = L & 31;
  const int arow = tid >> 3, acol = (tid & 7) * 4;  // A staging: 1 float4/thread
  const int akq = acol >> 3, aoff = acol & 7;

  floatx16 acc[2][2] = {};
  const float* xptr = X + (row0 + arow) * kD + acol;
  const __bf16* bptr = Wbf + ((size_t)(ct0 * 32) + l32) * 8;

  bf16x8 bE[4], bO[4];  // B fragments, even/odd slab double-buffer
  auto loadB = [&](bf16x8* dst, int s) {
#pragma unroll
    for (int kh = 0; kh < 2; ++kh) {
      const int kq = kh * 2 + lhalf;
      const __bf16* bq = bptr + (size_t)(s * 4 + kq) * 4096;
      dst[kh * 2 + 0] = *(const bf16x8*)bq;
      dst[kh * 2 + 1] = *(const bf16x8*)(bq + 256);  // +32 chunks = col+32
    }
  };
  auto stage = [&](int bufIdx, const float4& a) {
    bf16x4 av;
    av[0] = (__bf16)a.x; av[1] = (__bf16)a.y;
    av[2] = (__bf16)a.z; av[3] = (__bf16)a.w;
    *(bf16x4*)&As2[bufIdx][akq][arow][aoff] = av;
  };
  auto computeR = [&](int bufIdx, const bf16x8* bb) {
#pragma unroll
    for (int kh = 0; kh < 2; ++kh) {
      const int kq = kh * 2 + lhalf;
      const bf16x8 af0 = *(const bf16x8*)&As2[bufIdx][kq][l32][0];
      const bf16x8 af1 = *(const bf16x8*)&As2[bufIdx][kq][32 + l32][0];
      acc[0][0] = __builtin_amdgcn_mfma_f32_32x32x16_bf16(af0, bb[kh * 2 + 0], acc[0][0], 0, 0, 0);
      acc[0][1] = __builtin_amdgcn_mfma_f32_32x32x16_bf16(af0, bb[kh * 2 + 1], acc[0][1], 0, 0, 0);
      acc[1][0] = __builtin_amdgcn_mfma_f32_32x32x16_bf16(af1, bb[kh * 2 + 0], acc[1][0], 0, 0, 0);
      acc[1][1] = __builtin_amdgcn_mfma_f32_32x32x16_bf16(af1, bb[kh * 2 + 1], acc[1][1], 0, 0, 0);
    }
  };

  // prologue: B(0)->bE; stage A(0); X(1),X(2) in flight (2-deep)
  loadB(bE, 0);
  {
    const float4 a0 = *(const float4*)xptr;
    stage(0, a0);
  }
  float4 aA = *(const float4*)(xptr + 1 * 32);
  float4 aB = *(const float4*)(xptr + 2 * 32);
  asm volatile("s_waitcnt lgkmcnt(0)" ::: "memory");
  __builtin_amdgcn_s_barrier();

#pragma unroll 1
  for (int s = 0; s < 16; s += 2) {
    // ---- even slab s: B(s+1)->bO issued first (full slab to land) ----
    loadB(bO, s + 1);
    stage(1, aA);  // waits only aA's vmcnt; bO/aB stay in flight
    if (s + 3 < 16) aA = *(const float4*)(xptr + (s + 3) * 32);
    computeR(0, bE);
    asm volatile("s_waitcnt lgkmcnt(0)" ::: "memory");  // A ds_writes visible
    __builtin_amdgcn_s_barrier();                        // vmcnt NOT drained
    // ---- odd slab o=s+1: B(o+1)->bE; compute from bO ----
    const int o = s + 1;
    if (o < 15) {
      loadB(bE, o + 1);
      stage(0, aB);
      if (o + 3 < 16) aB = *(const float4*)(xptr + (o + 3) * 32);
    }
    computeR(1, bO);
    if (o < 15) {
      asm volatile("s_waitcnt lgkmcnt(0)" ::: "memory");
      __builtin_amdgcn_s_barrier();
    }
  }

  // ---- epilogue 1: column sums/sumsq -> LDS -> plain partial stores ----
  __syncthreads();
  sred[0][tid] = 0.f;
  sred[1][tid] = 0.f;
  __syncthreads();
#pragma unroll
  for (int c = 0; c < 2; ++c) {
    float s = 0.f, q = 0.f;
#pragma unroll
    for (int rt = 0; rt < 2; ++rt) {
#pragma unroll
      for (int r = 0; r < 16; ++r) {
        const float v = acc[rt][c][r];
        s += v;
        q += v * v;
      }
    }
    s += __shfl_xor(s, 32);
    q += __shfl_xor(q, 32);
    if (lhalf == 0) {
      atomicAdd(&sred[0][(ct0 + c) * 32 + l32], s);  // LDS atomics only
      atomicAdd(&sred[1][(ct0 + c) * 32 + l32], q);
    }
  }

  // ---- epilogue 1.5: fused raw chunk-EWMA (kL=16 rows per chunk) ----
  // v = sum_i a^(15-i) (1-a) wx_i; row-in-chunk i = (j&3)+8*(j>>2)+4*lhalf.
#pragma unroll
  for (int c = 0; c < 2; ++c) {
    const int col = (ct0 + c) * 32 + l32;
    const float a = clipa(alpha[col]);
    const float oma = 1.0f - a;
    const float a2 = a * a, a4 = a2 * a2, a8 = a4 * a4;
    float wgt[8];
    wgt[0] = a8 * a2 * a; wgt[1] = a8 * a2; wgt[2] = a8 * a; wgt[3] = a8;
    wgt[4] = a2 * a;      wgt[5] = a2;      wgt[6] = a;      wgt[7] = 1.0f;
    const float mult = (lhalf == 0) ? a4 * oma : oma;
#pragma unroll
    for (int j = 0; j < 8; ++j) wgt[j] *= mult;
#pragma unroll
    for (int rt = 0; rt < 2; ++rt) {
#pragma unroll
      for (int c32 = 0; c32 < 2; ++c32) {
        float S = 0.f;
#pragma unroll
        for (int j = 0; j < 8; ++j) S += wgt[j] * acc[rt][c][c32 * 8 + j];
        S += __shfl_xor(S, 32);
        if (lhalf == 0) {
          const int g = swz * 4 + rt * 2 + c32;  // global chunk id (swizzled rows)
          vbuf[(size_t)g * kH + col] = S;
        }
      }
    }
  }

  // ---- epilogue 2: store Wx bf16, packed dword pairs via shfl ----
  // C/D layout (32x32): col = lane&31, row = 4*(lane>>5) + (reg&3) + 8*(reg>>2)
#pragma unroll
  for (int rt = 0; rt < 2; ++rt) {
#pragma unroll
    for (int c = 0; c < 2; ++c) {
      const int col = (ct0 + c) * 32 + l32;
#pragma unroll
      for (int r = 0; r < 16; ++r) {
        const int row = rt * 32 + 4 * lhalf + (r & 3) + 8 * (r >> 2);
        const unsigned short u = __builtin_bit_cast(unsigned short, (__bf16)acc[rt][c][r]);
        const unsigned un = __shfl_down((unsigned)u, 1);
        if ((l32 & 1) == 0)
          *(unsigned*)(Wxb + (row0 + row) * (size_t)kH + col) = (unsigned)u | (un << 16);
      }
    }
  }
  __syncthreads();
  partial[(size_t)blockIdx.x * 1024 + tid] = sred[0][tid];
  partial[(size_t)blockIdx.x * 1024 + 512 + tid] = sred[1][tid];
}

// ---------- K2: reduce per-block partials (40 blocks x 25 rows = 1000) ----------
__global__ __launch_bounds__(512) void red1_k(const float* __restrict__ partial,
                                              float* __restrict__ sums) {
  const int tid = threadIdx.x;
  const int r0 = blockIdx.x * 25;
  float s0 = 0.f, s1 = 0.f;
#pragma unroll 5
  for (int r = 0; r < 25; ++r) {
    s0 += partial[(size_t)(r0 + r) * 1024 + tid];
    s1 += partial[(size_t)(r0 + r) * 1024 + 512 + tid];
  }
  atomicAdd(&sums[tid], s0);        // 40-deep contention: negligible
  atomicAdd(&sums[kH + tid], s1);
}

// ---------- K3: finalize BN params + chunk scan; ustart IN-PLACE in vbuf ----------
// grid = 32 (one block per batch). prm: [0]=scale [512]=shift [1024]=a [1536]=1-a.
// Per chunk: read v, overwrite slot with chunk-start u, advance u=a16*u+sc*v+shc.
__global__ __launch_bounds__(512) void fin_scan_k(const float* __restrict__ sums,
                                                  const float* __restrict__ alpha,
                                                  const float* __restrict__ gamma,
                                                  const float* __restrict__ beta,
                                                  const float* __restrict__ ut0,
                                                  float* __restrict__ prm,
                                                  float* __restrict__ vbuf) {
  const int h = threadIdx.x;
  const int b = blockIdx.x;
  const float inv_n = 1.0f / (float)kM;
  const float mean = sums[h] * inv_n;
  const float var = sums[kH + h] * inv_n - mean * mean;
  const float sc = gamma[h] * rsqrtf(var + 1e-5f);
  const float sh = beta[h] - mean * sc;
  const float a = clipa(alpha[h]);
  if (b == 0) {
    prm[h] = sc;
    prm[kH + h] = sh;
    prm[2 * kH + h] = a;
    prm[3 * kH + h] = 1.0f - a;
  }
  const float a16 = pow16(a);
  const float shc = sh * (1.0f - a16);
  float u = ut0[(size_t)b * kH + h];
  float vc[kG];
#pragma unroll 1
  for (int cb = 0; cb < kC; cb += kG) {
#pragma unroll
    for (int j = 0; j < kG; ++j)
      vc[j] = vbuf[((size_t)b * kC + cb + j) * kH + h];  // prefetch group
#pragma unroll
    for (int j = 0; j < kG; ++j) {
      vbuf[((size_t)b * kC + cb + j) * kH + h] = u;      // chunk-start u
      u = a16 * u + sc * vc[j] + shc;
    }
  }
}

// ---------- K4: softmax accum — 5 waves/block = 1 group, LDS reduce ----------
// 800 blocks x 320 threads; wave wv owns chunk grp*5+wv (same batch b).
// Lane owns 8 cols (h0=lane*8): coalesced ushort8 row loads; per-row denom =
// 6-level shfl_xor; no main-loop LDS/barriers. One cross-wave LDS reduce +
// single atomic set from wave 0 -> 410K atomics, 25-deep (R12's proven depth).
__global__ __launch_bounds__(320) void soft_k(const unsigned short* __restrict__ Wxb,
                                              const float* __restrict__ prm,
                                              const float* __restrict__ ustart,
                                              float* __restrict__ out) {
  __shared__ float red[kG - 1][64][8];  // 8 KB
  const int tid = threadIdx.x;
  const int wv = tid >> 6, lane = tid & 63;
  const int bc = blockIdx.x;              // group 0..799
  const int b = bc / kNG, grp = bc % kNG;
  const int c = grp * kG + wv;            // this wave's chunk
  const int h0 = lane * 8;

  float sc[8], sh[8], av[8], om[8], u[8], acc[8];
  *(float4*)&sc[0] = *(const float4*)(prm + h0);
  *(float4*)&sc[4] = *(const float4*)(prm + h0 + 4);
  *(float4*)&sh[0] = *(const float4*)(prm + kH + h0);
  *(float4*)&sh[4] = *(const float4*)(prm + kH + h0 + 4);
  *(float4*)&av[0] = *(const float4*)(prm + 2 * kH + h0);
  *(float4*)&av[4] = *(const float4*)(prm + 2 * kH + h0 + 4);
  *(float4*)&om[0] = *(const float4*)(prm + 3 * kH + h0);
  *(float4*)&om[4] = *(const float4*)(prm + 3 * kH + h0 + 4);
  const float* up = ustart + ((size_t)b * kC + c) * kH + h0;
  *(float4*)&u[0] = *(const float4*)up;
  *(float4*)&u[4] = *(const float4*)(up + 4);
#pragma unroll
  for (int j = 0; j < 8; ++j) acc[j] = 0.f;

  const unsigned short* base = Wxb + ((size_t)b * kT + (size_t)c * kL) * kH + h0;
#pragma unroll
  for (int i = 0; i < kL; ++i) {
    const u16x8 v = *(const u16x8*)(base + (size_t)i * kH);
    float e[8];
    float ls = 0.f;
#pragma unroll
    for (int j = 0; j < 8; ++j) {
      const float wvx = bf2f(v[j]) * sc[j] + sh[j];
      u[j] = av[j] * u[j] + om[j] * wvx;
      e[j] = __expf(u[j]);  // |u| <~ 2 after BN+EWMA damping
      ls += e[j];
    }
#pragma unroll
    for (int off = 32; off > 0; off >>= 1) ls += __shfl_xor(ls, off);
    const float zi = 1.0f / ls;
#pragma unroll
    for (int j = 0; j < 8; ++j) acc[j] += e[j] * zi;
  }

  // cross-wave reduce: waves 1..4 park in LDS; wave 0 sums + one atomic set
  if (wv > 0) {
#pragma unroll
    for (int j = 0; j < 8; ++j) red[wv - 1][lane][j] = acc[j];
  }
  __syncthreads();
  if (wv == 0) {
#pragma unroll
    for (int k = 0; k < kG - 1; ++k)
#pragma unroll
      for (int j = 0; j < 8; ++j) acc[j] += red[k][lane][j];
#pragma unroll
    for (int j = 0; j < 8; ++j)
      atomicAdd(&out[(size_t)b * kH + h0 + j], acc[j]);  // 25-deep per address
  }
}

}  // namespace

extern "C" void kernel_launch(void* const* d_in, const int* in_sizes, int n_in,
                              void* d_out, int out_size, void* d_ws, size_t ws_size,
                              hipStream_t stream) {
  const float* x = (const float*)d_in[0];      // [32,2000,512]
  const float* Wm = (const float*)d_in[1];     // [512,512]
  // d_in[2] = b: unused — BN mean subtraction cancels the bias exactly
  const float* alpha = (const float*)d_in[3];
  const float* gamma = (const float*)d_in[4];
  const float* beta = (const float*)d_in[5];
  const float* ut0 = (const float*)d_in[6];
  float* out = (float*)d_out;                  // [32,1,512]

  float* wsp = (float*)d_ws;
  float* vbuf = wsp;                                   // 32*125*512 = 2,048,000 f
  float* partial = vbuf + (size_t)kB * kC * kH;        // 1000*1024 f
  float* sums = partial + (size_t)1000 * 1024;         // 1024 f
  float* prm = sums + 2 * kH;                          // 2048 f
  __bf16* Wbf = (__bf16*)(prm + 4 * kH);               // 262144 bf16 (16B-aligned)
  unsigned short* Wxb = (unsigned short*)(Wbf + (size_t)kH * kD);  // 65.5 MB

  wcvt_k<<<128, 256, 0, stream>>>(Wm, Wbf, sums, out);  // also zeroes sums+out
  gemm_k<<<kNB, 512, 0, stream>>>(x, Wbf, alpha, Wxb, vbuf, partial);
  red1_k<<<40, 512, 0, stream>>>(partial, sums);
  fin_scan_k<<<kB, 512, 0, stream>>>(sums, alpha, gamma, beta, ut0, prm, vbuf);
  soft_k<<<kB * kNG, 320, 0, stream>>>(Wxb, prm, vbuf, out);
}